// Round 13
// baseline (134.501 us; speedup 1.0000x reference)
//
#include <hip/hip_runtime.h>
#include <cstdint>
#include <cstddef>

#define B 64
#define S 2048
#define D 512
#define H 128
#define Q 4
#define QH 32
#define KTOP 4
#define NROWS (B * S)
#define NEGV -1e9f
#define NCH 32                  // pool chunks per b
#define SC (S / NCH)            // 64
#define ZPB (S / 128)           // evidence blocks per b = 16

typedef __bf16 bf16x8 __attribute__((ext_vector_type(8)));
typedef float f32x4 __attribute__((ext_vector_type(4)));
typedef unsigned short us8 __attribute__((ext_vector_type(8)));

// ---------------------------------------------------------------------------
// helpers
// ---------------------------------------------------------------------------
__device__ __forceinline__ unsigned hasbyte(unsigned v, unsigned c) {
    unsigned x = v ^ (c * 0x01010101u);
    return (x - 0x01010101u) & ~x & 0x80808080u;
}

__device__ __forceinline__ void split_f32(float x, unsigned short& hi, unsigned short& lo) {
    unsigned bx = __float_as_uint(x);
    hi = (unsigned short)(bx >> 16);
    float fh = __uint_as_float(bx & 0xFFFF0000u);
    lo = (unsigned short)(__float_as_uint(x - fh) >> 16);
}

__device__ __forceinline__ float tanh_f(float x) {
    float e = __expf(2.f * x);
    return 1.f - __fdividef(2.f, e + 1.f);
}

__device__ __forceinline__ void gll16(const void* g, void* l) {
    __builtin_amdgcn_global_load_lds(
        (const __attribute__((address_space(1))) unsigned int*)g,
        (__attribute__((address_space(3))) unsigned int*)l, 16, 0, 0);
}

// ---------------------------------------------------------------------------
// K0 (merged prep, R8-proven): blocks 0..255 -> W1 split into transposed bf16
// hi/lo planes [h][k]; block 256 -> mask dtype detect; blocks 257..768 ->
// quality MLP per (b,s). modes: 0=u8,1=i32,2=i64,3=f32,4=f64
// ---------------------------------------------------------------------------
__global__ __launch_bounds__(256) void prep_kernel(
    const float* __restrict__ W1, unsigned short* __restrict__ bh,
    unsigned short* __restrict__ bl, const unsigned char* __restrict__ m,
    int* __restrict__ mode, const float* __restrict__ segq,
    const float* __restrict__ qW1, const float* __restrict__ qb1,
    const float* __restrict__ qw2, const float* __restrict__ qb2,
    float* __restrict__ qual) {
    const int t = threadIdx.x;
    const int bid = blockIdx.x;
    if (bid < 256) {
        int i = bid * 256 + t;  // i = h*512 + k
        int h = i >> 9, k = i & 511;
        float x = W1[(size_t)k * H + h];
        unsigned short hv, lv;
        split_f32(x, hv, lv);
        bh[i] = hv;
        bl[i] = lv;
        return;
    }
    if (bid == 256) {
        __shared__ int fF0, fF, fB, fO4;
        if (t == 0) { fF0 = 0; fF = 0; fB = 0; fO4 = 0; }
        __syncthreads();
        const uint4* mv = (const uint4*)m;
        int a = 0, bb = 0, c = 0, d = 0;
        for (int i = t; i < NROWS / 16; i += 256) {
            uint4 v = mv[i];
            if (hasbyte(v.x, 0xF0u) | hasbyte(v.y, 0xF0u) | hasbyte(v.z, 0xF0u) | hasbyte(v.w, 0xF0u)) a = 1;
            if (hasbyte(v.x, 0x3Fu) | hasbyte(v.y, 0x3Fu) | hasbyte(v.z, 0x3Fu) | hasbyte(v.w, 0x3Fu) |
                hasbyte(v.x, 0x80u) | hasbyte(v.y, 0x80u) | hasbyte(v.z, 0x80u) | hasbyte(v.w, 0x80u)) bb = 1;
            if ((v.x & 0xFFFFFF00u) | (v.y & 0xFFFFFF00u) | (v.z & 0xFFFFFF00u) | (v.w & 0xFFFFFF00u)) c = 1;
            if ((v.y & 0xFFu) | (v.w & 0xFFu)) d = 1;
        }
        if (a) atomicOr(&fF0, 1);
        if (bb) atomicOr(&fF, 1);
        if (c) atomicOr(&fB, 1);
        if (d) atomicOr(&fO4, 1);
        __syncthreads();
        if (t == 0) {
            int md;
            if (fF0) md = 4;
            else if (fF) md = 3;
            else if (fB) md = 0;
            else if (fO4) md = 1;
            else md = 2;
            *mode = md;
        }
        return;
    }
    // quality MLP blocks
    __shared__ float sW[Q * QH];
    __shared__ float sb1[QH];
    __shared__ float sw2[QH];
    __shared__ float sb2v;
    if (t < Q * QH) sW[t] = qW1[t];
    if (t >= 128 && t < 128 + QH) sb1[t - 128] = qb1[t - 128];
    if (t >= 160 && t < 160 + QH) sw2[t - 160] = qw2[t - 160];
    if (t == 192) sb2v = qb2[0];
    __syncthreads();
    const int i = (bid - 257) * 256 + t;
    float4 sq = *reinterpret_cast<const float4*>(&segq[(size_t)i * Q]);
    float s = 0.f;
#pragma unroll
    for (int h = 0; h < QH; ++h) {
        float a = sq.x * sW[h] + sq.y * sW[QH + h] + sq.z * sW[2 * QH + h] + sq.w * sW[3 * QH + h] + sb1[h];
        a = fmaxf(a, 0.f);
        s += a * sw2[h];
    }
    qual[i] = s + sb2v;
}

// ---------------------------------------------------------------------------
// K1: evidence via split bf16 MFMA. Same 128x128 tile / BK=32 / swizzles as
// R12 champion, but 512 thr = 8 waves (4x2), wave tile 32x64 -> acc[2][4] =
// 32 VGPR (vs 64). Goal: total VGPR <=128 -> 16 waves/CU (2 blocks x 8 waves)
// instead of 8. NO launch_bounds min-blocks arg (R7/R9: caps force spills).
// Epilogue: tanh + w2 dot, inline mask decode, comb + ew + Zpart.
// ---------------------------------------------------------------------------
__global__ __launch_bounds__(512) void evidence_mfma_kernel(
    const float* __restrict__ feats, const unsigned short* __restrict__ wbh,
    const unsigned short* __restrict__ wbl, const float* __restrict__ b1g,
    const float* __restrict__ w2g, const float* __restrict__ b2g,
    const float* __restrict__ qual, const void* __restrict__ mraw,
    const int* __restrict__ mode, float* __restrict__ comb,
    float* __restrict__ ew, float* __restrict__ Zpart) {
    __shared__ unsigned short sAh[128][32];
    __shared__ unsigned short sAl[128][32];
    __shared__ unsigned short sBh[128][32];
    __shared__ unsigned short sBl[128][32];
    __shared__ float red[128][2];
    __shared__ float sew[128];

    const int t = threadIdx.x;
    const int lane = t & 63;
    const int wid = t >> 6;        // 0..7
    const int wm = wid >> 1;       // 0..3: row group of 32
    const int wn = wid & 1;        // 0..1: h group of 64
    const int l16 = lane & 15, lk = lane >> 4;
    const int row0 = blockIdx.x * 128;
    const int md = *mode;

    f32x4 acc[2][4];
#pragma unroll
    for (int mf = 0; mf < 2; ++mf)
#pragma unroll
        for (int nf = 0; nf < 4; ++nf) acc[mf][nf] = (f32x4)0.f;

    // A staging map: thread -> (row ar = t>>2, octet ao = t&3); swizzled pos
    const int ar = t >> 2;
    const int ao = t & 3;
    const int po = ao ^ ((ar >> 1) & 3);
    const float* fsrc = feats + (size_t)(row0 + ar) * D + ao * 8;

    // B staging (gll16): linear LDS dest; per-lane PRE-SWIZZLED global octet.
    // Wave wid covers rows [wid*16, wid*16+16); 1 call per plane per wave.
    const int hr = wid * 16 + (lane >> 2);
    const int ko = ((lane & 3) ^ ((hr >> 1) & 3)) * 8;  // source octet (ushorts)
    char* dBh = (char*)&sBh[0][0] + wid * 1024;
    char* dBl = (char*)&sBl[0][0] + wid * 1024;

    for (int kc = 0; kc < D; kc += 32) {
        gll16(wbh + (size_t)hr * D + kc + ko, dBh);
        gll16(wbl + (size_t)hr * D + kc + ko, dBl);

        float f[8];
        *reinterpret_cast<float4*>(&f[0]) = *reinterpret_cast<const float4*>(fsrc + kc + 0);
        *reinterpret_cast<float4*>(&f[4]) = *reinterpret_cast<const float4*>(fsrc + kc + 4);
        us8 vh, vl;
#pragma unroll
        for (int j = 0; j < 8; ++j) {
            unsigned short hh, ll;
            split_f32(f[j], hh, ll);
            vh[j] = hh; vl[j] = ll;
        }
        *reinterpret_cast<us8*>(&sAh[ar][po * 8]) = vh;
        *reinterpret_cast<us8*>(&sAl[ar][po * 8]) = vl;

        __syncthreads();

        bf16x8 ah[2], al[2];
#pragma unroll
        for (int mf = 0; mf < 2; ++mf) {
            int rr = wm * 32 + mf * 16 + l16;
            int sp = (lk ^ ((rr >> 1) & 3)) * 8;   // un-swizzle on read
            ah[mf] = *reinterpret_cast<const bf16x8*>(&sAh[rr][sp]);
            al[mf] = *reinterpret_cast<const bf16x8*>(&sAl[rr][sp]);
        }
        // B fragments loaded per-nf (R11): 8 live VGPR
#pragma unroll
        for (int nf = 0; nf < 4; ++nf) {
            int hh = wn * 64 + nf * 16 + l16;
            int sp = (lk ^ ((hh >> 1) & 3)) * 8;   // un-swizzle on read
            bf16x8 bh = *reinterpret_cast<const bf16x8*>(&sBh[hh][sp]);
            bf16x8 bl = *reinterpret_cast<const bf16x8*>(&sBl[hh][sp]);
#pragma unroll
            for (int mf = 0; mf < 2; ++mf) {
                acc[mf][nf] = __builtin_amdgcn_mfma_f32_16x16x32_bf16(ah[mf], bh, acc[mf][nf], 0, 0, 0);
                acc[mf][nf] = __builtin_amdgcn_mfma_f32_16x16x32_bf16(ah[mf], bl, acc[mf][nf], 0, 0, 0);
                acc[mf][nf] = __builtin_amdgcn_mfma_f32_16x16x32_bf16(al[mf], bh, acc[mf][nf], 0, 0, 0);
            }
        }
        __syncthreads();
    }

    // ---- epilogue: tanh + w2 dot, reduce over 16 col-lanes ----
    float b1v[4], w2v[4];
#pragma unroll
    for (int nf = 0; nf < 4; ++nf) {
        int hh = wn * 64 + nf * 16 + l16;
        b1v[nf] = b1g[hh];
        w2v[nf] = w2g[hh];
    }
#pragma unroll
    for (int mf = 0; mf < 2; ++mf)
#pragma unroll
        for (int r2 = 0; r2 < 4; ++r2) {
            float s = 0.f;
#pragma unroll
            for (int nf = 0; nf < 4; ++nf) s += tanh_f(acc[mf][nf][r2] + b1v[nf]) * w2v[nf];
            s += __shfl_xor(s, 1, 16);
            s += __shfl_xor(s, 2, 16);
            s += __shfl_xor(s, 4, 16);
            s += __shfl_xor(s, 8, 16);
            if (l16 == 0) red[wm * 32 + mf * 16 + lk * 4 + r2][wn] = s;
        }
    __syncthreads();

    // ---- per-row: mask decode + comb + ew ----
    if (t < 128) {
        const int row = row0 + t;
        float mv;
        switch (md) {
            case 0: mv = ((const unsigned char*)mraw)[row] ? 1.f : 0.f; break;
            case 1: mv = ((const int*)mraw)[row] ? 1.f : 0.f; break;
            case 2: mv = ((const long long*)mraw)[row] ? 1.f : 0.f; break;
            case 3: mv = (((const float*)mraw)[row] != 0.f) ? 1.f : 0.f; break;
            default: mv = (((const double*)mraw)[row] != 0.0) ? 1.f : 0.f; break;
        }
        float e = red[t][0] + red[t][1] + b2g[0];
        float c = (mv != 0.f) ? (e + qual[row]) : NEGV;
        comb[row] = c;
        float x = __expf(c);  // exp(-1e9) flushes to 0
        ew[row] = x;
        sew[t] = x;
    }
    __syncthreads();
    if (t < 64) {
        float z = sew[t] + sew[t + 64];
#pragma unroll
        for (int o = 32; o > 0; o >>= 1) z += __shfl_xor(z, o, 64);
        if (t == 0) Zpart[blockIdx.x] = z;
    }
}

// ---------------------------------------------------------------------------
// K2: partial pooling with UNNORMALIZED ew (R2-proven), float4 lanes.
// grid (NCH, B), 256 thr
// ---------------------------------------------------------------------------
__global__ __launch_bounds__(256) void pool_partial_kernel(
    const float* __restrict__ feats, const float* __restrict__ ew, float* __restrict__ part) {
    const int b = blockIdx.y, ch = blockIdx.x, t = threadIdx.x;
    const int s0 = ch * SC;
    __shared__ float sw[SC];
    __shared__ float4 redp[256];
    if (t < SC) sw[t] = ew[(size_t)b * S + s0 + t];
    __syncthreads();
    const int dq = (t & 127) * 4;
    const int rp = t >> 7;
    float4 a = {0.f, 0.f, 0.f, 0.f};
    const float* fp = feats + ((size_t)b * S + s0 + rp) * D + dq;
    for (int s = rp; s < SC; s += 2) {
        float wv = sw[s];
        if (wv != 0.f) {  // wave-uniform (128-thread row groups)
            float4 f = *reinterpret_cast<const float4*>(fp);
            a.x += wv * f.x; a.y += wv * f.y; a.z += wv * f.z; a.w += wv * f.w;
        }
        fp += 2 * D;
    }
    redp[t] = a;
    __syncthreads();
    if (t < 128) {
        float4 o = redp[t], o2 = redp[t + 128];
        o.x += o2.x; o.y += o2.y; o.z += o2.z; o.w += o2.w;
        *reinterpret_cast<float4*>(&part[((size_t)(b * NCH + ch)) * D + dq]) = o;
    }
}

// ---------------------------------------------------------------------------
// K3: per-b finalize: Z, weights=exp(comb)/Z, top-4, part-reduce, gather, mix
// ---------------------------------------------------------------------------
__global__ __launch_bounds__(256) void finalize_kernel(
    const float* __restrict__ comb, const float* __restrict__ Zpart,
    const float* __restrict__ part, const float* __restrict__ feats,
    float* __restrict__ o_weights, float* __restrict__ o_tidx, float* __restrict__ o_tval,
    float* __restrict__ o_attn, float* __restrict__ o_topk, float* __restrict__ o_pooled) {
    __shared__ float sinv;
    __shared__ float mvv[256 * 4];
    __shared__ int mii[256 * 4];
    __shared__ int sti[4];
    __shared__ float stv[4];
    __shared__ float sdn;
    const int b = blockIdx.x, t = threadIdx.x;
    const float* row = comb + (size_t)b * S;

    if (t == 0) {
        float z = 0.f;
#pragma unroll
        for (int j = 0; j < ZPB; ++j) z += Zpart[b * ZPB + j];
        sinv = 1.f / fmaxf(z, 1e-8f);
    }
    __syncthreads();
    const float inv = sinv;

    float tv[4] = {-3e38f, -3e38f, -3e38f, -3e38f};
    int ti[4] = {1 << 30, 1 << 30, 1 << 30, 1 << 30};
    for (int s = t; s < S; s += 256) {
        float v = row[s];
        o_weights[(size_t)b * S + s] = __expf(v) * inv;
        if (v > tv[3]) {
            tv[3] = v; ti[3] = s;
#pragma unroll
            for (int k = 3; k > 0; --k) {
                bool up = (tv[k] > tv[k - 1]) || (tv[k] == tv[k - 1] && ti[k] < ti[k - 1]);
                if (up) {
                    float fv = tv[k]; tv[k] = tv[k - 1]; tv[k - 1] = fv;
                    int ii = ti[k]; ti[k] = ti[k - 1]; ti[k - 1] = ii;
                }
            }
        }
    }
#pragma unroll
    for (int k = 0; k < 4; ++k) { mvv[t * 4 + k] = tv[k]; mii[t * 4 + k] = ti[k]; }
    __syncthreads();
    for (int st = 128; st >= 1; st >>= 1) {
        if (t < st) {
            float av[4], bv[4];
            int ai[4], bi[4];
#pragma unroll
            for (int k = 0; k < 4; ++k) {
                av[k] = mvv[t * 4 + k]; ai[k] = mii[t * 4 + k];
                bv[k] = mvv[(t + st) * 4 + k]; bi[k] = mii[(t + st) * 4 + k];
            }
            float rv[4]; int ri[4];
            int i = 0, j = 0;
            for (int o = 0; o < 4; ++o) {
                bool ta = (av[i] > bv[j]) || (av[i] == bv[j] && ai[i] < bi[j]);
                if (ta) { rv[o] = av[i]; ri[o] = ai[i]; ++i; }
                else { rv[o] = bv[j]; ri[o] = bi[j]; ++j; }
            }
#pragma unroll
            for (int k = 0; k < 4; ++k) { mvv[t * 4 + k] = rv[k]; mii[t * 4 + k] = ri[k]; }
        }
        __syncthreads();
    }
    if (t == 0) {
        float dn = 0.f;
#pragma unroll
        for (int k = 0; k < 4; ++k) {
            int idx = mii[k];
            int valid = (mvv[k] > -1e8f) ? 1 : 0;
            sti[k] = idx;
            stv[k] = (float)valid;
            o_tidx[b * 4 + k] = (float)idx;
            o_tval[b * 4 + k] = (float)valid;
            dn += (float)valid;
        }
        sdn = fmaxf(dn, 1.f);
    }
    __syncthreads();

    const int i0 = sti[0], i1 = sti[1], i2 = sti[2], i3 = sti[3];
    const float v0 = stv[0], v1 = stv[1], v2 = stv[2], v3 = stv[3];
    const float inv_dn = 1.f / sdn;
    for (int d = t; d < D; d += 256) {
        float s = 0.f;
#pragma unroll
        for (int ch = 0; ch < NCH; ++ch) s += part[((size_t)(b * NCH + ch)) * D + d];
        s *= inv;
        float tk = v0 * feats[((size_t)b * S + i0) * D + d] + v1 * feats[((size_t)b * S + i1) * D + d] +
                   v2 * feats[((size_t)b * S + i2) * D + d] + v3 * feats[((size_t)b * S + i3) * D + d];
        tk *= inv_dn;
        o_attn[(size_t)b * D + d] = s;
        o_topk[(size_t)b * D + d] = tk;
        o_pooled[(size_t)b * D + d] = 0.5f * s + 0.5f * tk;
    }
}

// ---------------------------------------------------------------------------
extern "C" void kernel_launch(void* const* d_in, const int* in_sizes, int n_in,
                              void* d_out, int out_size, void* d_ws, size_t ws_size,
                              hipStream_t stream) {
    const float* feats = (const float*)d_in[0];
    const void* maskraw = d_in[1];
    const float* segq = (const float*)d_in[2];
    const float* W1 = (const float*)d_in[3];
    const float* b1 = (const float*)d_in[4];
    const float* w2 = (const float*)d_in[5];
    const float* b2 = (const float*)d_in[6];
    const float* qW1 = (const float*)d_in[7];
    const float* qb1 = (const float*)d_in[8];
    const float* qw2 = (const float*)d_in[9];
    const float* qb2 = (const float*)d_in[10];

    char* ws = (char*)d_ws;
    int* mode = (int*)ws;                          // 16 B
    float* comb = (float*)(ws + 16);               // B*S
    float* ewb = comb + NROWS;                     // B*S
    float* qual = ewb + NROWS;                     // B*S
    float* part = qual + NROWS;                    // B*NCH*D (4 MiB)
    float* Zpart = part + (size_t)B * NCH * D;     // 1024
    unsigned short* wsBh = (unsigned short*)(Zpart + 1024);  // H*D
    unsigned short* wsBl = wsBh + (size_t)H * D;

    float* out = (float*)d_out;
    float* o_pooled = out;                         // B*D
    float* o_weights = out + (size_t)B * D;        // B*S
    float* o_attn = o_weights + (size_t)B * S;     // B*D
    float* o_topk = o_attn + (size_t)B * D;        // B*D
    float* o_tidx = o_topk + (size_t)B * D;        // B*K
    float* o_tval = o_tidx + (size_t)B * KTOP;     // B*K

    prep_kernel<<<257 + NROWS / 256, 256, 0, stream>>>(
        W1, wsBh, wsBl, (const unsigned char*)maskraw, mode,
        segq, qW1, qb1, qw2, qb2, qual);
    evidence_mfma_kernel<<<NROWS / 128, 512, 0, stream>>>(
        feats, wsBh, wsBl, b1, w2, b2, qual, maskraw, mode, comb, ewb, Zpart);
    pool_partial_kernel<<<dim3(NCH, B), 256, 0, stream>>>(feats, ewb, part);
    finalize_kernel<<<B, 256, 0, stream>>>(comb, Zpart, part, feats, o_weights,
                                           o_tidx, o_tval, o_attn, o_topk, o_pooled);
}

// Round 14
// 132.071 us; speedup vs baseline: 1.0184x; 1.0184x over previous
//
#include <hip/hip_runtime.h>
#include <cstdint>
#include <cstddef>

#define B 64
#define S 2048
#define D 512
#define H 128
#define Q 4
#define QH 32
#define KTOP 4
#define NROWS (B * S)
#define NEGV -1e9f
#define NCH 32                  // pool chunks per b
#define SC (S / NCH)            // 64
#define ZPB (S / 128)           // evidence blocks per b = 16

typedef __bf16 bf16x8 __attribute__((ext_vector_type(8)));
typedef float f32x4 __attribute__((ext_vector_type(4)));
typedef unsigned short us8 __attribute__((ext_vector_type(8)));

// ---------------------------------------------------------------------------
// helpers
// ---------------------------------------------------------------------------
__device__ __forceinline__ unsigned hasbyte(unsigned v, unsigned c) {
    unsigned x = v ^ (c * 0x01010101u);
    return (x - 0x01010101u) & ~x & 0x80808080u;
}

__device__ __forceinline__ void split_f32(float x, unsigned short& hi, unsigned short& lo) {
    unsigned bx = __float_as_uint(x);
    hi = (unsigned short)(bx >> 16);
    float fh = __uint_as_float(bx & 0xFFFF0000u);
    lo = (unsigned short)(__float_as_uint(x - fh) >> 16);
}

__device__ __forceinline__ float tanh_f(float x) {
    float e = __expf(2.f * x);
    return 1.f - __fdividef(2.f, e + 1.f);
}

__device__ __forceinline__ void gll16(const void* g, void* l) {
    __builtin_amdgcn_global_load_lds(
        (const __attribute__((address_space(1))) unsigned int*)g,
        (__attribute__((address_space(3))) unsigned int*)l, 16, 0, 0);
}

// ---------------------------------------------------------------------------
// K0 (merged prep, R8-proven): blocks 0..255 -> W1 split into transposed bf16
// hi/lo planes [h][k]; block 256 -> mask dtype detect; blocks 257..768 ->
// quality MLP per (b,s). modes: 0=u8,1=i32,2=i64,3=f32,4=f64
// ---------------------------------------------------------------------------
__global__ __launch_bounds__(256) void prep_kernel(
    const float* __restrict__ W1, unsigned short* __restrict__ bh,
    unsigned short* __restrict__ bl, const unsigned char* __restrict__ m,
    int* __restrict__ mode, const float* __restrict__ segq,
    const float* __restrict__ qW1, const float* __restrict__ qb1,
    const float* __restrict__ qw2, const float* __restrict__ qb2,
    float* __restrict__ qual) {
    const int t = threadIdx.x;
    const int bid = blockIdx.x;
    if (bid < 256) {
        int i = bid * 256 + t;  // i = h*512 + k
        int h = i >> 9, k = i & 511;
        float x = W1[(size_t)k * H + h];
        unsigned short hv, lv;
        split_f32(x, hv, lv);
        bh[i] = hv;
        bl[i] = lv;
        return;
    }
    if (bid == 256) {
        __shared__ int fF0, fF, fB, fO4;
        if (t == 0) { fF0 = 0; fF = 0; fB = 0; fO4 = 0; }
        __syncthreads();
        const uint4* mv = (const uint4*)m;
        int a = 0, bb = 0, c = 0, d = 0;
        for (int i = t; i < NROWS / 16; i += 256) {
            uint4 v = mv[i];
            if (hasbyte(v.x, 0xF0u) | hasbyte(v.y, 0xF0u) | hasbyte(v.z, 0xF0u) | hasbyte(v.w, 0xF0u)) a = 1;
            if (hasbyte(v.x, 0x3Fu) | hasbyte(v.y, 0x3Fu) | hasbyte(v.z, 0x3Fu) | hasbyte(v.w, 0x3Fu) |
                hasbyte(v.x, 0x80u) | hasbyte(v.y, 0x80u) | hasbyte(v.z, 0x80u) | hasbyte(v.w, 0x80u)) bb = 1;
            if ((v.x & 0xFFFFFF00u) | (v.y & 0xFFFFFF00u) | (v.z & 0xFFFFFF00u) | (v.w & 0xFFFFFF00u)) c = 1;
            if ((v.y & 0xFFu) | (v.w & 0xFFu)) d = 1;
        }
        if (a) atomicOr(&fF0, 1);
        if (bb) atomicOr(&fF, 1);
        if (c) atomicOr(&fB, 1);
        if (d) atomicOr(&fO4, 1);
        __syncthreads();
        if (t == 0) {
            int md;
            if (fF0) md = 4;
            else if (fF) md = 3;
            else if (fB) md = 0;
            else if (fO4) md = 1;
            else md = 2;
            *mode = md;
        }
        return;
    }
    // quality MLP blocks
    __shared__ float sW[Q * QH];
    __shared__ float sb1[QH];
    __shared__ float sw2[QH];
    __shared__ float sb2v;
    if (t < Q * QH) sW[t] = qW1[t];
    if (t >= 128 && t < 128 + QH) sb1[t - 128] = qb1[t - 128];
    if (t >= 160 && t < 160 + QH) sw2[t - 160] = qw2[t - 160];
    if (t == 192) sb2v = qb2[0];
    __syncthreads();
    const int i = (bid - 257) * 256 + t;
    float4 sq = *reinterpret_cast<const float4*>(&segq[(size_t)i * Q]);
    float s = 0.f;
#pragma unroll
    for (int h = 0; h < QH; ++h) {
        float a = sq.x * sW[h] + sq.y * sW[QH + h] + sq.z * sW[2 * QH + h] + sq.w * sW[3 * QH + h] + sb1[h];
        a = fmaxf(a, 0.f);
        s += a * sw2[h];
    }
    qual[i] = s + sb2v;
}

// ---------------------------------------------------------------------------
// K1: evidence via split bf16 MFMA (R12 champion, verbatim).
// Per block: 128 rows x 128 h, BK=32; 256 thr = 4 waves 2x2; 3 MFMA/frag pair.
// XOR octet swizzle p = o ^ ((row>>1)&3) on A (write+read) and B
// (pre-swizzled gll16 source + swizzled read). Per-nf B loads (R11).
// Epilogue: tanh + w2 dot, inline mask decode, comb + ew + Zpart.
// ---------------------------------------------------------------------------
__global__ __launch_bounds__(256) void evidence_mfma_kernel(
    const float* __restrict__ feats, const unsigned short* __restrict__ wbh,
    const unsigned short* __restrict__ wbl, const float* __restrict__ b1g,
    const float* __restrict__ w2g, const float* __restrict__ b2g,
    const float* __restrict__ qual, const void* __restrict__ mraw,
    const int* __restrict__ mode, float* __restrict__ comb,
    float* __restrict__ ew, float* __restrict__ Zpart) {
    __shared__ unsigned short sAh[128][32];
    __shared__ unsigned short sAl[128][32];
    __shared__ unsigned short sBh[128][32];
    __shared__ unsigned short sBl[128][32];
    __shared__ float red[128][2];
    __shared__ float sew[128];

    const int t = threadIdx.x;
    const int lane = t & 63;
    const int wid = t >> 6;
    const int wm = wid >> 1, wn = wid & 1;
    const int l16 = lane & 15, lk = lane >> 4;
    const int row0 = blockIdx.x * 128;
    const int md = *mode;

    f32x4 acc[4][4];
#pragma unroll
    for (int mf = 0; mf < 4; ++mf)
#pragma unroll
        for (int nf = 0; nf < 4; ++nf) acc[mf][nf] = (f32x4)0.f;

    // A staging map: thread -> (row ar, k-half); octet swizzle s=(ar>>1)&3
    const int ar = t >> 1;
    const int akh = (t & 1) * 16;
    const int asw = (ar >> 1) & 3;
    const int po0 = ((t & 1) * 2 + 0) ^ asw;   // swizzled octet for first us8
    const int po1 = ((t & 1) * 2 + 1) ^ asw;   // swizzled octet for second us8
    const float* fsrc = feats + (size_t)(row0 + ar) * D + akh;

    // B staging (gll16): linear LDS dest; per-lane PRE-SWIZZLED global octet.
    // Call c covers rows hb_c = (wid*2+c)*16 + (lane>>2); LDS octet = lane&3.
    const int h0r = (wid * 2 + 0) * 16 + (lane >> 2);
    const int h1r = (wid * 2 + 1) * 16 + (lane >> 2);
    const int k0o = ((lane & 3) ^ ((h0r >> 1) & 3)) * 8;  // source octet (ushorts)
    const int k1o = ((lane & 3) ^ ((h1r >> 1) & 3)) * 8;
    char* sBh0 = (char*)&sBh[0][0] + (wid * 2 + 0) * 1024;
    char* sBh1 = (char*)&sBh[0][0] + (wid * 2 + 1) * 1024;
    char* sBl0 = (char*)&sBl[0][0] + (wid * 2 + 0) * 1024;
    char* sBl1 = (char*)&sBl[0][0] + (wid * 2 + 1) * 1024;

    for (int kc = 0; kc < D; kc += 32) {
        gll16(wbh + (size_t)h0r * D + kc + k0o, sBh0);
        gll16(wbh + (size_t)h1r * D + kc + k1o, sBh1);
        gll16(wbl + (size_t)h0r * D + kc + k0o, sBl0);
        gll16(wbl + (size_t)h1r * D + kc + k1o, sBl1);

        float f[16];
        *reinterpret_cast<float4*>(&f[0]) = *reinterpret_cast<const float4*>(fsrc + kc + 0);
        *reinterpret_cast<float4*>(&f[4]) = *reinterpret_cast<const float4*>(fsrc + kc + 4);
        *reinterpret_cast<float4*>(&f[8]) = *reinterpret_cast<const float4*>(fsrc + kc + 8);
        *reinterpret_cast<float4*>(&f[12]) = *reinterpret_cast<const float4*>(fsrc + kc + 12);
        us8 vh0, vh1, vl0, vl1;
#pragma unroll
        for (int j = 0; j < 8; ++j) {
            unsigned short hh, ll;
            split_f32(f[j], hh, ll);
            vh0[j] = hh; vl0[j] = ll;
        }
#pragma unroll
        for (int j = 0; j < 8; ++j) {
            unsigned short hh, ll;
            split_f32(f[8 + j], hh, ll);
            vh1[j] = hh; vl1[j] = ll;
        }
        *reinterpret_cast<us8*>(&sAh[ar][po0 * 8]) = vh0;
        *reinterpret_cast<us8*>(&sAh[ar][po1 * 8]) = vh1;
        *reinterpret_cast<us8*>(&sAl[ar][po0 * 8]) = vl0;
        *reinterpret_cast<us8*>(&sAl[ar][po1 * 8]) = vl1;

        __syncthreads();

        bf16x8 ah[4], al[4];
#pragma unroll
        for (int mf = 0; mf < 4; ++mf) {
            int rr = wm * 64 + mf * 16 + l16;
            int sp = (lk ^ ((rr >> 1) & 3)) * 8;   // un-swizzle on read
            ah[mf] = *reinterpret_cast<const bf16x8*>(&sAh[rr][sp]);
            al[mf] = *reinterpret_cast<const bf16x8*>(&sAl[rr][sp]);
        }
        // B fragments loaded per-nf (R11): live B-frag VGPR 8 instead of 32
#pragma unroll
        for (int nf = 0; nf < 4; ++nf) {
            int hh = wn * 64 + nf * 16 + l16;
            int sp = (lk ^ ((hh >> 1) & 3)) * 8;   // un-swizzle on read
            bf16x8 bh = *reinterpret_cast<const bf16x8*>(&sBh[hh][sp]);
            bf16x8 bl = *reinterpret_cast<const bf16x8*>(&sBl[hh][sp]);
#pragma unroll
            for (int mf = 0; mf < 4; ++mf) {
                acc[mf][nf] = __builtin_amdgcn_mfma_f32_16x16x32_bf16(ah[mf], bh, acc[mf][nf], 0, 0, 0);
                acc[mf][nf] = __builtin_amdgcn_mfma_f32_16x16x32_bf16(ah[mf], bl, acc[mf][nf], 0, 0, 0);
                acc[mf][nf] = __builtin_amdgcn_mfma_f32_16x16x32_bf16(al[mf], bh, acc[mf][nf], 0, 0, 0);
            }
        }
        __syncthreads();
    }

    // ---- epilogue: tanh + w2 dot, reduce over 16 col-lanes ----
    float b1v[4], w2v[4];
#pragma unroll
    for (int nf = 0; nf < 4; ++nf) {
        int hh = wn * 64 + nf * 16 + l16;
        b1v[nf] = b1g[hh];
        w2v[nf] = w2g[hh];
    }
    float rs[4][4];
#pragma unroll
    for (int mf = 0; mf < 4; ++mf)
#pragma unroll
        for (int r2 = 0; r2 < 4; ++r2) {
            float s = 0.f;
#pragma unroll
            for (int nf = 0; nf < 4; ++nf) s += tanh_f(acc[mf][nf][r2] + b1v[nf]) * w2v[nf];
            s += __shfl_xor(s, 1, 16);
            s += __shfl_xor(s, 2, 16);
            s += __shfl_xor(s, 4, 16);
            s += __shfl_xor(s, 8, 16);
            rs[mf][r2] = s;
        }
    if (l16 == 0) {
#pragma unroll
        for (int mf = 0; mf < 4; ++mf)
#pragma unroll
            for (int r2 = 0; r2 < 4; ++r2) red[wm * 64 + mf * 16 + lk * 4 + r2][wn] = rs[mf][r2];
    }
    __syncthreads();

    // ---- per-row: mask decode + comb + ew ----
    if (t < 128) {
        const int row = row0 + t;
        float mv;
        switch (md) {
            case 0: mv = ((const unsigned char*)mraw)[row] ? 1.f : 0.f; break;
            case 1: mv = ((const int*)mraw)[row] ? 1.f : 0.f; break;
            case 2: mv = ((const long long*)mraw)[row] ? 1.f : 0.f; break;
            case 3: mv = (((const float*)mraw)[row] != 0.f) ? 1.f : 0.f; break;
            default: mv = (((const double*)mraw)[row] != 0.0) ? 1.f : 0.f; break;
        }
        float e = red[t][0] + red[t][1] + b2g[0];
        float c = (mv != 0.f) ? (e + qual[row]) : NEGV;
        comb[row] = c;
        float x = __expf(c);  // exp(-1e9) flushes to 0
        ew[row] = x;
        sew[t] = x;
    }
    __syncthreads();
    if (t < 64) {
        float z = sew[t] + sew[t + 64];
#pragma unroll
        for (int o = 32; o > 0; o >>= 1) z += __shfl_xor(z, o, 64);
        if (t == 0) Zpart[blockIdx.x] = z;
    }
}

// ---------------------------------------------------------------------------
// K2: partial pooling with UNNORMALIZED ew (R2-proven), float4 lanes.
// grid (NCH, B), 256 thr
// ---------------------------------------------------------------------------
__global__ __launch_bounds__(256) void pool_partial_kernel(
    const float* __restrict__ feats, const float* __restrict__ ew, float* __restrict__ part) {
    const int b = blockIdx.y, ch = blockIdx.x, t = threadIdx.x;
    const int s0 = ch * SC;
    __shared__ float sw[SC];
    __shared__ float4 redp[256];
    if (t < SC) sw[t] = ew[(size_t)b * S + s0 + t];
    __syncthreads();
    const int dq = (t & 127) * 4;
    const int rp = t >> 7;
    float4 a = {0.f, 0.f, 0.f, 0.f};
    const float* fp = feats + ((size_t)b * S + s0 + rp) * D + dq;
    for (int s = rp; s < SC; s += 2) {
        float wv = sw[s];
        if (wv != 0.f) {  // wave-uniform (128-thread row groups)
            float4 f = *reinterpret_cast<const float4*>(fp);
            a.x += wv * f.x; a.y += wv * f.y; a.z += wv * f.z; a.w += wv * f.w;
        }
        fp += 2 * D;
    }
    redp[t] = a;
    __syncthreads();
    if (t < 128) {
        float4 o = redp[t], o2 = redp[t + 128];
        o.x += o2.x; o.y += o2.y; o.z += o2.z; o.w += o2.w;
        *reinterpret_cast<float4*>(&part[((size_t)(b * NCH + ch)) * D + dq]) = o;
    }
}

// ---------------------------------------------------------------------------
// K3: per-b finalize: Z, weights=exp(comb)/Z, top-4, part-reduce, gather, mix
// ---------------------------------------------------------------------------
__global__ __launch_bounds__(256) void finalize_kernel(
    const float* __restrict__ comb, const float* __restrict__ Zpart,
    const float* __restrict__ part, const float* __restrict__ feats,
    float* __restrict__ o_weights, float* __restrict__ o_tidx, float* __restrict__ o_tval,
    float* __restrict__ o_attn, float* __restrict__ o_topk, float* __restrict__ o_pooled) {
    __shared__ float sinv;
    __shared__ float mvv[256 * 4];
    __shared__ int mii[256 * 4];
    __shared__ int sti[4];
    __shared__ float stv[4];
    __shared__ float sdn;
    const int b = blockIdx.x, t = threadIdx.x;
    const float* row = comb + (size_t)b * S;

    if (t == 0) {
        float z = 0.f;
#pragma unroll
        for (int j = 0; j < ZPB; ++j) z += Zpart[b * ZPB + j];
        sinv = 1.f / fmaxf(z, 1e-8f);
    }
    __syncthreads();
    const float inv = sinv;

    float tv[4] = {-3e38f, -3e38f, -3e38f, -3e38f};
    int ti[4] = {1 << 30, 1 << 30, 1 << 30, 1 << 30};
    for (int s = t; s < S; s += 256) {
        float v = row[s];
        o_weights[(size_t)b * S + s] = __expf(v) * inv;
        if (v > tv[3]) {
            tv[3] = v; ti[3] = s;
#pragma unroll
            for (int k = 3; k > 0; --k) {
                bool up = (tv[k] > tv[k - 1]) || (tv[k] == tv[k - 1] && ti[k] < ti[k - 1]);
                if (up) {
                    float fv = tv[k]; tv[k] = tv[k - 1]; tv[k - 1] = fv;
                    int ii = ti[k]; ti[k] = ti[k - 1]; ti[k - 1] = ii;
                }
            }
        }
    }
#pragma unroll
    for (int k = 0; k < 4; ++k) { mvv[t * 4 + k] = tv[k]; mii[t * 4 + k] = ti[k]; }
    __syncthreads();
    for (int st = 128; st >= 1; st >>= 1) {
        if (t < st) {
            float av[4], bv[4];
            int ai[4], bi[4];
#pragma unroll
            for (int k = 0; k < 4; ++k) {
                av[k] = mvv[t * 4 + k]; ai[k] = mii[t * 4 + k];
                bv[k] = mvv[(t + st) * 4 + k]; bi[k] = mii[(t + st) * 4 + k];
            }
            float rv[4]; int ri[4];
            int i = 0, j = 0;
            for (int o = 0; o < 4; ++o) {
                bool ta = (av[i] > bv[j]) || (av[i] == bv[j] && ai[i] < bi[j]);
                if (ta) { rv[o] = av[i]; ri[o] = ai[i]; ++i; }
                else { rv[o] = bv[j]; ri[o] = bi[j]; ++j; }
            }
#pragma unroll
            for (int k = 0; k < 4; ++k) { mvv[t * 4 + k] = rv[k]; mii[t * 4 + k] = ri[k]; }
        }
        __syncthreads();
    }
    if (t == 0) {
        float dn = 0.f;
#pragma unroll
        for (int k = 0; k < 4; ++k) {
            int idx = mii[k];
            int valid = (mvv[k] > -1e8f) ? 1 : 0;
            sti[k] = idx;
            stv[k] = (float)valid;
            o_tidx[b * 4 + k] = (float)idx;
            o_tval[b * 4 + k] = (float)valid;
            dn += (float)valid;
        }
        sdn = fmaxf(dn, 1.f);
    }
    __syncthreads();

    const int i0 = sti[0], i1 = sti[1], i2 = sti[2], i3 = sti[3];
    const float v0 = stv[0], v1 = stv[1], v2 = stv[2], v3 = stv[3];
    const float inv_dn = 1.f / sdn;
    for (int d = t; d < D; d += 256) {
        float s = 0.f;
#pragma unroll
        for (int ch = 0; ch < NCH; ++ch) s += part[((size_t)(b * NCH + ch)) * D + d];
        s *= inv;
        float tk = v0 * feats[((size_t)b * S + i0) * D + d] + v1 * feats[((size_t)b * S + i1) * D + d] +
                   v2 * feats[((size_t)b * S + i2) * D + d] + v3 * feats[((size_t)b * S + i3) * D + d];
        tk *= inv_dn;
        o_attn[(size_t)b * D + d] = s;
        o_topk[(size_t)b * D + d] = tk;
        o_pooled[(size_t)b * D + d] = 0.5f * s + 0.5f * tk;
    }
}

// ---------------------------------------------------------------------------
extern "C" void kernel_launch(void* const* d_in, const int* in_sizes, int n_in,
                              void* d_out, int out_size, void* d_ws, size_t ws_size,
                              hipStream_t stream) {
    const float* feats = (const float*)d_in[0];
    const void* maskraw = d_in[1];
    const float* segq = (const float*)d_in[2];
    const float* W1 = (const float*)d_in[3];
    const float* b1 = (const float*)d_in[4];
    const float* w2 = (const float*)d_in[5];
    const float* b2 = (const float*)d_in[6];
    const float* qW1 = (const float*)d_in[7];
    const float* qb1 = (const float*)d_in[8];
    const float* qw2 = (const float*)d_in[9];
    const float* qb2 = (const float*)d_in[10];

    char* ws = (char*)d_ws;
    int* mode = (int*)ws;                          // 16 B
    float* comb = (float*)(ws + 16);               // B*S
    float* ewb = comb + NROWS;                     // B*S
    float* qual = ewb + NROWS;                     // B*S
    float* part = qual + NROWS;                    // B*NCH*D (4 MiB)
    float* Zpart = part + (size_t)B * NCH * D;     // 1024
    unsigned short* wsBh = (unsigned short*)(Zpart + 1024);  // H*D
    unsigned short* wsBl = wsBh + (size_t)H * D;

    float* out = (float*)d_out;
    float* o_pooled = out;                         // B*D
    float* o_weights = out + (size_t)B * D;        // B*S
    float* o_attn = o_weights + (size_t)B * S;     // B*D
    float* o_topk = o_attn + (size_t)B * D;        // B*D
    float* o_tidx = o_topk + (size_t)B * D;        // B*K
    float* o_tval = o_tidx + (size_t)B * KTOP;     // B*K

    prep_kernel<<<257 + NROWS / 256, 256, 0, stream>>>(
        W1, wsBh, wsBl, (const unsigned char*)maskraw, mode,
        segq, qW1, qb1, qw2, qb2, qual);
    evidence_mfma_kernel<<<NROWS / 128, 256, 0, stream>>>(
        feats, wsBh, wsBl, b1, w2, b2, qual, maskraw, mode, comb, ewb, Zpart);
    pool_partial_kernel<<<dim3(NCH, B), 256, 0, stream>>>(feats, ewb, part);
    finalize_kernel<<<B, 256, 0, stream>>>(comb, Zpart, part, feats, o_weights,
                                           o_tidx, o_tval, o_attn, o_topk, o_pooled);
}